// Round 8
// baseline (922.509 us; speedup 1.0000x reference)
//
#include <hip/hip_runtime.h>
#include <math.h>

#define HWDIM 128
#define IMG   (HWDIM * HWDIM)       // 16384
#define PLANE (4 * 64 * IMG)        // elems of one [B,64,H,W] tensor

typedef __attribute__((ext_vector_type(8))) short bf16x8;
typedef __attribute__((ext_vector_type(4))) float f32x4;
typedef __attribute__((ext_vector_type(4))) int   i32x4;

// Pin a 16B value into VGPRs at this program point: forces the feeding load
// to have ISSUED (and completed) here, preventing the compiler from sinking
// batched loads into serial load->wait->use chains.
#define PINV(x) do { i32x4 _pt = __builtin_bit_cast(i32x4, (x)); \
                     asm volatile("" : "+v"(_pt));               \
                     (x) = __builtin_bit_cast(__typeof__(x), _pt); } while (0)
#define PINS(x) asm volatile("" : "+v"(x))

__device__ __forceinline__ unsigned short f2bf(float f) {
    unsigned u = __builtin_bit_cast(unsigned, f);
    u += 0x7FFFu + ((u >> 16) & 1u);          // RNE
    return (unsigned short)(u >> 16);
}
__device__ __forceinline__ float bf2f(unsigned short h) {
    unsigned u = ((unsigned)h) << 16;
    return __builtin_bit_cast(float, u);
}
__device__ __forceinline__ float sigmoidf_(float x) {
    return 1.f / (1.f + __expf(-x));
}
__device__ __forceinline__ float tanhf_(float x) {
    return 1.f - 2.f / (__expf(2.f * x) + 1.f);
}

// ---- weight prep: W_cell[256][128][3][3] -> Wg2[9][256][128] bf16
//                   W_seq [64][64][3][3]   -> Ws2[9][64][64]   bf16
__global__ void prep_weights_kernel(const float* __restrict__ Wc,
                                    const float* __restrict__ Ws,
                                    unsigned short* __restrict__ Wg2,
                                    unsigned short* __restrict__ Ws2) {
    int i = blockIdx.x * 256 + threadIdx.x;
    if (i < 9 * 256 * 128) {
        int tap = i >> 15, r = i & 32767, co = r >> 7, ci = r & 127;
        Wg2[i] = f2bf(Wc[(co * 128 + ci) * 9 + tap]);
    }
    if (i < 9 * 64 * 64) {
        int tap = i / 4096, r = i & 4095, co = r >> 6, ci = r & 63;
        Ws2[i] = f2bf(Ws[(co * 64 + ci) * 9 + tap]);
    }
}

// ---- seq conv, ALL timesteps in one dispatch: x fp32 CHW -> xout fp32 CHW
__global__ __launch_bounds__(256, 3) void seq_conv_mfma(
    const float* __restrict__ xinp,           // [8][4][64][128][128]
    const unsigned short* __restrict__ Ws2,   // [9][64][64]
    const float* __restrict__ bseq,           // [64]
    float* __restrict__ xout)                 // [8][4][64][128][128]
{
    __shared__ __align__(16) unsigned short tile[3 * 66 * 72];  // 28512 B

    const int tid = threadIdx.x;
    const int sb  = (blockIdx.x & 7) * 1024 + (blockIdx.x >> 3);  // XCD swizzle
    const int t   = sb >> 10;
    const int rem = sb & 1023;
    const int b   = rem >> 8;
    const int y   = (rem >> 1) & 127;
    const int x0  = (rem & 1) * 64;

    const float* xb = xinp + (size_t)t * PLANE + (size_t)b * 64 * IMG;

    const int lane = tid & 63;
    const int w = tid >> 6;                 // cout stripe w*16
    const int ln = lane & 15, lg = lane >> 4;

    // ---- phase 1: ISSUE all staging + weight loads ----
    float4 fa[6], fb[6];
    #pragma unroll
    for (int it = 0; it < 6; ++it) {
        int i = tid + it * 256;
        int xq = i & 15, cip = (i >> 4) & 31, ry = i >> 9;
        int gy = y - 1 + ry;
        int ci = cip * 2;
        float4 va = {0.f, 0.f, 0.f, 0.f}, vb = {0.f, 0.f, 0.f, 0.f};
        if ((unsigned)gy < 128u) {
            va = *(const float4*)(xb + (size_t)ci * IMG + gy * HWDIM + x0 + xq * 4);
            vb = *(const float4*)(xb + (size_t)(ci + 1) * IMG + gy * HWDIM + x0 + xq * 4);
        }
        fa[it] = va; fb[it] = vb;
    }
    float ea = 0.f, eb = 0.f;
    {
        int e = tid & 1, cip = (tid >> 1) & 31, ry = tid >> 6;
        int xt = e ? 65 : 0;
        int gy = y - 1 + ry, gx = x0 - 1 + xt;
        int ci = cip * 2;
        if (tid < 192 && (unsigned)gy < 128u && (unsigned)gx < 128u) {
            ea = xb[(size_t)ci * IMG + gy * HWDIM + gx];
            eb = xb[(size_t)(ci + 1) * IMG + gy * HWDIM + gx];
        }
    }
    const unsigned short* wbase = Ws2 + (size_t)(w * 16 + ln) * 64 + lg * 8;
    bf16x8 wreg[18];
    #pragma unroll
    for (int st = 0; st < 18; ++st) {
        int tap = st >> 1, kk = st & 1;
        wreg[st] = *(const bf16x8*)(wbase + tap * 4096 + kk * 32);
    }

    // ---- pin staging batch (one wait for all) ----
    #pragma unroll
    for (int it = 0; it < 6; ++it) { PINV(fa[it]); PINV(fb[it]); }
    PINS(ea); PINS(eb);

    // ---- ds_writes ----
    #pragma unroll
    for (int it = 0; it < 6; ++it) {
        int i = tid + it * 256;
        int xq = i & 15, cip = (i >> 4) & 31, ry = i >> 9;
        int ci = cip * 2;
        const float* pa = (const float*)&fa[it];
        const float* pb = (const float*)&fb[it];
        #pragma unroll
        for (int j = 0; j < 4; ++j) {
            unsigned pk = (unsigned)f2bf(pa[j]) | ((unsigned)f2bf(pb[j]) << 16);
            *(unsigned*)(tile + (ry * 66 + 1 + xq * 4 + j) * 72 + ci) = pk;
        }
    }
    if (tid < 192) {
        int e = tid & 1, cip = (tid >> 1) & 31, ry = tid >> 6;
        int xt = e ? 65 : 0;
        unsigned pk = (unsigned)f2bf(ea) | ((unsigned)f2bf(eb) << 16);
        *(unsigned*)(tile + (ry * 66 + xt) * 72 + cip * 2) = pk;
    }

    // ---- pin weights (batch-issued above, waited here, live in regs) ----
    #pragma unroll
    for (int st = 0; st < 18; ++st) PINV(wreg[st]);

    __syncthreads();

    f32x4 acc[4];
    #pragma unroll
    for (int n = 0; n < 4; ++n) acc[n] = (f32x4){0.f, 0.f, 0.f, 0.f};

    #pragma unroll
    for (int st = 0; st < 18; ++st) {
        const int tap = st >> 1, kk = st & 1;
        const int dy = tap / 3, dxx = tap % 3;
        #pragma unroll
        for (int n = 0; n < 4; ++n) {
            bf16x8 imf = *(const bf16x8*)(tile + (dy * 66 + n * 16 + ln + dxx) * 72 + kk * 32 + lg * 8);
            acc[n] = __builtin_amdgcn_mfma_f32_16x16x32_bf16(wreg[st], imf, acc[n], 0, 0, 0);
        }
    }

    // epilogue: xout fp32 CHW, coalesced (lane -> px)
    float* xout_t = xout + (size_t)t * PLANE;
    const int co = w * 16 + lg * 4;
    #pragma unroll
    for (int r = 0; r < 4; ++r) {
        const float bv = bseq[co + r];
        float* dst = xout_t + ((size_t)b * 64 + co + r) * IMG + (size_t)y * HWDIM + x0;
        #pragma unroll
        for (int n = 0; n < 4; ++n)
            dst[n * 16 + ln] = acc[n][r] + bv;
    }
}

// ---- gates conv (Cin=128 -> 256 gate-striped) + in-register LSTM epilogue
__global__ __launch_bounds__(256, 3) void gates_lstm_mfma(
    const float* __restrict__ xo,             // xout_t [4][64][128][128] fp32
    const unsigned short* __restrict__ hin,   // [4][128][128][64] bf16
    const unsigned short* __restrict__ Wg2,   // [9][256][128]
    const float* __restrict__ bcell,          // [256]
    unsigned short* __restrict__ hout,        // [4][128][128][64] bf16
    unsigned short* __restrict__ cbuf,        // [4][128][128][64] bf16 in/out
    float* __restrict__ h32)                  // h_final fp32 CHW (t=7) or null
{
    __shared__ __align__(16) unsigned short tile[3 * 66 * 136];  // 53856 B

    const int tid = threadIdx.x;
    const int bid = (blockIdx.x & 7) * 128 + (blockIdx.x >> 3);  // XCD swizzle
    const int b  = bid >> 8;
    const int y  = (bid >> 1) & 127;
    const int x0 = (bid & 1) * 64;

    const int lane = tid & 63;
    const int w = tid >> 6;                 // cout stripe (within each gate)
    const int ln = lane & 15, lg = lane >> 4;
    const int s = w * 16;
    const int ch = s + ln;

    // ---- phase 1: ISSUE all staging loads (x, h, edges, c-prefetch) ----
    const float* xb = xo + (size_t)b * 64 * IMG;
    float4 fa[6], fb[6];
    #pragma unroll
    for (int it = 0; it < 6; ++it) {
        int i = tid + it * 256;
        int xq = i & 15, cip = (i >> 4) & 31, ry = i >> 9;
        int gy = y - 1 + ry;
        int ci = cip * 2;
        float4 va = {0.f, 0.f, 0.f, 0.f}, vb = {0.f, 0.f, 0.f, 0.f};
        if ((unsigned)gy < 128u) {
            va = *(const float4*)(xb + (size_t)ci * IMG + gy * HWDIM + x0 + xq * 4);
            vb = *(const float4*)(xb + (size_t)(ci + 1) * IMG + gy * HWDIM + x0 + xq * 4);
        }
        fa[it] = va; fb[it] = vb;
    }
    float ea = 0.f, eb2 = 0.f;
    {
        int e = tid & 1, cip = (tid >> 1) & 31, ry = tid >> 6;
        int xt = e ? 65 : 0;
        int gy = y - 1 + ry, gx = x0 - 1 + xt;
        int ci = cip * 2;
        if (tid < 192 && (unsigned)gy < 128u && (unsigned)gx < 128u) {
            ea  = xb[(size_t)ci * IMG + gy * HWDIM + gx];
            eb2 = xb[(size_t)(ci + 1) * IMG + gy * HWDIM + gx];
        }
    }
    const unsigned short* hb = hin + (size_t)b * 128 * 128 * 64;
    i32x4 hv[6];
    #pragma unroll
    for (int it = 0; it < 6; ++it) {
        int i = tid + it * 256;          // (ry*64 + xtm)*8 + g ; xt = xtm+1
        int g = i & 7, xtm = (i >> 3) & 63, ry = i >> 9;
        int gy = y - 1 + ry, gx = x0 + xtm;
        i32x4 v = {0, 0, 0, 0};
        if ((unsigned)gy < 128u)
            v = *(const i32x4*)(hb + ((size_t)gy * 128 + gx) * 64 + g * 8);
        hv[it] = v;
    }
    i32x4 he = {0, 0, 0, 0};
    {
        int g = tid & 7, e = (tid >> 3) & 1, ry = tid >> 4;
        int xt = e ? 65 : 0;
        int gy = y - 1 + ry, gx = x0 - 1 + xt;
        if (tid < 48 && (unsigned)gy < 128u && (unsigned)gx < 128u)
            he = *(const i32x4*)(hb + ((size_t)gy * 128 + gx) * 64 + g * 8);
    }
    // c-prefetch: 16 scalar loads (hides the pointwise tail's latency)
    int cpre[16];
    #pragma unroll
    for (int m = 0; m < 4; ++m)
        #pragma unroll
        for (int r = 0; r < 4; ++r) {
            const int px = m * 16 + lg * 4 + r;
            const size_t pixbase = ((size_t)b * 128 + y) * 128 + x0 + px;
            cpre[m * 4 + r] = (int)cbuf[pixbase * 64 + ch];
        }

    // ---- pin staging batch ----
    #pragma unroll
    for (int it = 0; it < 6; ++it) { PINV(fa[it]); PINV(fb[it]); PINV(hv[it]); }
    PINV(he); PINS(ea); PINS(eb2);
    #pragma unroll
    for (int j = 0; j < 16; ++j) PINS(cpre[j]);

    // ---- ds_writes ----
    #pragma unroll
    for (int it = 0; it < 6; ++it) {
        int i = tid + it * 256;
        int xq = i & 15, cip = (i >> 4) & 31, ry = i >> 9;
        int ci = cip * 2;
        const float* pa = (const float*)&fa[it];
        const float* pb = (const float*)&fb[it];
        #pragma unroll
        for (int j = 0; j < 4; ++j) {
            unsigned pk = (unsigned)f2bf(pa[j]) | ((unsigned)f2bf(pb[j]) << 16);
            *(unsigned*)(tile + (ry * 66 + 1 + xq * 4 + j) * 136 + ci) = pk;
        }
    }
    if (tid < 192) {
        int e = tid & 1, cip = (tid >> 1) & 31, ry = tid >> 6;
        int xt = e ? 65 : 0;
        unsigned pk = (unsigned)f2bf(ea) | ((unsigned)f2bf(eb2) << 16);
        *(unsigned*)(tile + (ry * 66 + xt) * 136 + cip * 2) = pk;
    }
    #pragma unroll
    for (int it = 0; it < 6; ++it) {
        int i = tid + it * 256;
        int g = i & 7, xtm = (i >> 3) & 63, ry = i >> 9;
        *(i32x4*)(tile + (ry * 66 + 1 + xtm) * 136 + 64 + g * 8) = hv[it];
    }
    if (tid < 48) {
        int g = tid & 7, e = (tid >> 3) & 1, ry = tid >> 4;
        int xt = e ? 65 : 0;
        *(i32x4*)(tile + (ry * 66 + xt) * 136 + 64 + g * 8) = he;
    }

    __syncthreads();

    f32x4 acc[4][4];                        // [m_px][gate]
    #pragma unroll
    for (int m = 0; m < 4; ++m)
        #pragma unroll
        for (int g = 0; g < 4; ++g) acc[m][g] = (f32x4){0.f, 0.f, 0.f, 0.f};

    // ---- per-tap: batch-issue 16 weight frags, pin (one wait), 64 MFMAs ----
    const unsigned short* wbase = Wg2 + (size_t)ch * 128 + lg * 8;
    #pragma unroll
    for (int tap = 0; tap < 9; ++tap) {
        const int dy = tap / 3, dxx = tap % 3;
        bf16x8 wf[4][4];                    // [g][kk]
        #pragma unroll
        for (int g = 0; g < 4; ++g)
            #pragma unroll
            for (int kk = 0; kk < 4; ++kk)
                wf[g][kk] = *(const bf16x8*)(wbase + tap * 32768 + g * 8192 + kk * 32);
        #pragma unroll
        for (int g = 0; g < 4; ++g)
            #pragma unroll
            for (int kk = 0; kk < 4; ++kk) PINV(wf[g][kk]);
        #pragma unroll
        for (int kk = 0; kk < 4; ++kk) {
            #pragma unroll
            for (int m = 0; m < 4; ++m) {
                bf16x8 af = *(const bf16x8*)(tile + (dy * 66 + m * 16 + ln + dxx) * 136 + kk * 32 + lg * 8);
                #pragma unroll
                for (int g = 0; g < 4; ++g)
                    acc[m][g] = __builtin_amdgcn_mfma_f32_16x16x32_bf16(af, wf[g][kk], acc[m][g], 0, 0, 0);
            }
        }
    }

    // ---- in-register LSTM pointwise (c already prefetched) ----
    const float bi = bcell[ch], bf_ = bcell[64 + ch];
    const float bg = bcell[128 + ch], bo = bcell[192 + ch];

    #pragma unroll
    for (int m = 0; m < 4; ++m) {
        #pragma unroll
        for (int r = 0; r < 4; ++r) {
            const int px = m * 16 + lg * 4 + r;
            float gi = acc[m][0][r] + bi;
            float gf = acc[m][1][r] + bf_;
            float gg = acc[m][2][r] + bg;
            float go = acc[m][3][r] + bo;
            float si = sigmoidf_(gi);
            float sf = sigmoidf_(gf);
            float tg = tanhf_(gg);
            float so = sigmoidf_(go);
            const size_t pixbase = ((size_t)b * 128 + y) * 128 + x0 + px;
            const size_t cidx = pixbase * 64 + ch;
            float cold = bf2f((unsigned short)cpre[m * 4 + r]);
            float cn = sf * cold + si * tg;
            cbuf[cidx] = f2bf(cn);
            float hv2 = so * tanhf_(cn);
            hout[cidx] = f2bf(hv2);
            if (h32) h32[((size_t)b * 64 + ch) * IMG + (size_t)y * HWDIM + x0 + px] = hv2;
        }
    }
}

extern "C" void kernel_launch(void* const* d_in, const int* in_sizes, int n_in,
                              void* d_out, int out_size, void* d_ws, size_t ws_size,
                              hipStream_t stream) {
    const float* xinp   = (const float*)d_in[0]; // [8,4,64,128,128]
    const float* W_seq  = (const float*)d_in[1];
    const float* b_seq  = (const float*)d_in[2];
    const float* W_cell = (const float*)d_in[3];
    const float* b_cell = (const float*)d_in[4];

    float* out     = (float*)d_out;
    float* h_final = out;                    // [4,64,128,128] fp32
    float* xout    = out + PLANE;            // [8,4,64,128,128] fp32

    // ws (bf16 elems): c | h0 | h1 | Wg2 | Ws2   (~25.8 MB)
    unsigned short* cbuf = (unsigned short*)d_ws;
    unsigned short* hb0  = cbuf + PLANE;
    unsigned short* hb1  = hb0 + PLANE;
    unsigned short* Wg2  = hb1 + PLANE;
    unsigned short* Ws2  = Wg2 + 9 * 256 * 128;
    unsigned short* hbufs[2] = { hb0, hb1 };

    hipMemsetAsync(hb0,  0, (size_t)PLANE * sizeof(unsigned short), stream); // h0
    hipMemsetAsync(cbuf, 0, (size_t)PLANE * sizeof(unsigned short), stream); // c0

    prep_weights_kernel<<<1152, 256, 0, stream>>>(W_cell, W_seq, Wg2, Ws2);

    // all 8 timesteps' seq convs in one dispatch (independent of recurrence)
    seq_conv_mfma<<<8192, 256, 0, stream>>>(xinp, Ws2, b_seq, xout);

    for (int t = 0; t < 8; ++t) {
        gates_lstm_mfma<<<1024, 256, 0, stream>>>(
            xout + (size_t)t * PLANE, hbufs[t & 1], Wg2, b_cell,
            hbufs[(t + 1) & 1], cbuf,
            (t == 7) ? h_final : (float*)nullptr);
    }
}